// Round 12
// baseline (472.567 us; speedup 1.0000x reference)
//
#include <hip/hip_runtime.h>

// InjectionLayer: event proj + GCNConv diffusion + gated fuse.
// N=100000, E=1600000, EVENT_DIM=64, HID=128.
// R9: projgcn via MFMA with pre-repacked fragments (706->511us).
// R10: bucketed counting-sort CSR build (511->490us).
// R11: gather pre-scaled x + 8-deep MLP unroll (490->441us).
// R12/R13: chunked run-reservation passA, LDS bhist (441->318us).
// R14: gather fused into MFMA epilogue (318->310us).
// R17/R18: deeper ILP null; 128-thr reshape regressed. Random 256B rows
//      across 8 XCD-L2s is a ~2.5TB/s structural ceiling.
// R19: FEATURE-SLICED gather. x stored slice-major [8][N][16cols]
//      (3.2MB/slice fits one XCD's 4MB L2); slice = blockIdx&7 rides the
//      round-robin block->XCD dispatch; grid = 2048 = 8 blocks/CU all
//      co-resident. es/dif nontemporal. Epilogue reverts to R13 form.
// R20: R19 resubmit with BUG FIX: self-term x[n] was added in all 8
//      source-groups then cross-group-reduced -> counted 8x. Now added
//      once (group 0, post-reduction).

typedef unsigned short inj_u16;
typedef unsigned int   inj_u32;
typedef __attribute__((ext_vector_type(8))) short bf16x8;
typedef __attribute__((ext_vector_type(4))) float f32x4;

static constexpr int INJ_N  = 100000;
static constexpr int INJ_E  = 1600000;
static constexpr int INJ_H  = 128;
static constexpr int INJ_D  = 64;
static constexpr int INJ_NB = 196;   // ceil(N/512) buckets of 512 nodes
static constexpr int INJ_CH = 6400;  // edges per passA/bhist block
static constexpr int INJ_PB = 250;   // chunk blocks = E/6400

__device__ __forceinline__ float inj_b2f(inj_u16 h){
  union { inj_u32 u; float f; } c; c.u = ((inj_u32)h) << 16; return c.f;
}
__device__ __forceinline__ inj_u16 inj_f2b(float x){
  union { inj_u32 u; float f; } c; c.f = x;
  return (inj_u16)((c.u + 0x7FFFu + ((c.u >> 16) & 1u)) >> 16);
}
__device__ __forceinline__ float inj_lo(inj_u32 w){ return inj_b2f((inj_u16)(w & 0xFFFFu)); }
__device__ __forceinline__ float inj_hi(inj_u32 w){ return inj_b2f((inj_u16)(w >> 16)); }
__device__ __forceinline__ inj_u32 inj_pack(float a, float b){
  return ((inj_u32)inj_f2b(b) << 16) | (inj_u32)inj_f2b(a);
}
__device__ __forceinline__ float inj_ld1(const void* p, size_t i, int f32){
  return f32 ? ((const float*)p)[i] : inj_b2f(((const inj_u16*)p)[i]);
}
__device__ __forceinline__ float2 inj_ld2(const void* p, size_t pair, int f32){
  if (f32) return ((const float2*)p)[pair];
  inj_u32 w = ((const inj_u32*)p)[pair];
  float2 r; r.x = inj_lo(w); r.y = inj_hi(w);
  return r;
}

// ---- runtime format probes ----
__global__ void inj_flags(const int* eidx, const inj_u32* base, int* flags){
  int l = threadIdx.x & 63;
  unsigned long long nz = __ballot(eidx[2*l + 1] != 0);
  inj_u32 ex = (base[l] >> 7) & 0xFFu;
  unsigned long long inr = __ballot(ex >= 100u && ex <= 135u);
  if (threadIdx.x == 0){
    flags[0] = (nz == 0ull) ? 1 : 0;              // int64 edges?
    flags[1] = (__popcll(inr) >= 56) ? 0 : 1;     // 0 = bf16, 1 = f32
  }
}

__device__ __forceinline__ int inj_eread(const int* e, size_t i, int w64){
  return w64 ? e[2*i] : e[i];
}

// ---- bucket histogram: LDS per-block hist -> 196 global atomics/block ----
__global__ __launch_bounds__(256) void inj_bhist(const int* eidx, int* bhp,
                                                 const int* flags){
  __shared__ int h[INJ_NB];
  const int tid = threadIdx.x;
  const int e0 = blockIdx.x * INJ_CH;
  const int w64 = flags[0];
  for (int b = tid; b < INJ_NB; b += 256) h[b] = 0;
  __syncthreads();
  for (int i = tid; i < INJ_CH; i += 256){
    int dst = inj_eread(eidx, (size_t)INJ_E + e0 + i, w64);
    atomicAdd(&h[dst >> 9], 1);
  }
  __syncthreads();
  for (int b = tid; b < INJ_NB; b += 256)
    if (h[b]) atomicAdd(&bhp[b*16], h[b]);
}

// ---- scan bucket counts -> bucket bases + passA cursors ----
__global__ void inj_bscan(const int* bhp, int* bbase, int* bcurA, int* rowp){
  __shared__ int s[256];
  int tid = threadIdx.x;
  int v = (tid < INJ_NB) ? bhp[tid*16] : 0;
  s[tid] = v; __syncthreads();
  for (int off = 1; off < 256; off <<= 1){
    int t = (tid >= off) ? s[tid - off] : 0;
    __syncthreads();
    s[tid] += t;
    __syncthreads();
  }
  if (tid < INJ_NB){
    int base = s[tid] - v;          // exclusive prefix
    bbase[tid]    = base;
    bcurA[tid*16] = base;
  }
  if (tid == 0){ bbase[INJ_NB] = INJ_E; rowp[INJ_N] = INJ_E; }
}

// ---- pass A: chunked run-reservation scatter ----
__global__ __launch_bounds__(256) void inj_passA(
    const int* eidx, int* bcurA, inj_u32* pairs, const int* flags){
  __shared__ inj_u32 sedge[INJ_CH];
  __shared__ unsigned char sbkt[INJ_CH];
  __shared__ int scnt[INJ_NB];
  __shared__ int scur[INJ_NB];
  const int tid = threadIdx.x;
  const int e0 = blockIdx.x * INJ_CH;
  const int w64 = flags[0];
  for (int b = tid; b < INJ_NB; b += 256) scnt[b] = 0;
  __syncthreads();
  for (int i = tid; i < INJ_CH; i += 256){
    int src = inj_eread(eidx, (size_t)(e0 + i), w64);
    int dst = inj_eread(eidx, (size_t)INJ_E + e0 + i, w64);
    int b = dst >> 9;
    sedge[i] = (inj_u32)src | ((inj_u32)(dst & 511) << 17);
    sbkt[i] = (unsigned char)b;
    atomicAdd(&scnt[b], 1);
  }
  __syncthreads();
  for (int b = tid; b < INJ_NB; b += 256){
    int c = scnt[b];
    scur[b] = c ? atomicAdd(&bcurA[b*16], c) : 0;
  }
  __syncthreads();
  for (int i = tid; i < INJ_CH; i += 256){
    int b = sbkt[i];
    int pos = atomicAdd(&scur[b], 1);
    pairs[pos] = sedge[i];
  }
}

// ---- pass B: per 512-node bucket -- LDS count/scan -> rowp/dis, fill ----
__global__ __launch_bounds__(256) void inj_passB(
    const inj_u32* pairs, const int* bbase, int* rowp, float* dis, int* es){
  __shared__ int lcnt[512];
  __shared__ int lcur[512];
  __shared__ int ls[512];
  __shared__ int ws[256];
  const int b = blockIdx.x, tid = threadIdx.x;
  const int beg = bbase[b], endp = bbase[b+1];
  const int nbase = b << 9;
  const int nn = min(512, INJ_N - nbase);
  for (int i = tid; i < 512; i += 256) lcnt[i] = 0;
  __syncthreads();
  for (int p = beg + tid; p < endp; p += 256)
    atomicAdd(&lcnt[pairs[p] >> 17], 1);
  __syncthreads();
  // scan 512: 2 consecutive elems per thread, block-scan the pair sums
  int v0 = lcnt[2*tid], v1 = lcnt[2*tid + 1];
  int psum = v0 + v1;
  ws[tid] = psum; __syncthreads();
  for (int off = 1; off < 256; off <<= 1){
    int t = (tid >= off) ? ws[tid - off] : 0;
    __syncthreads();
    ws[tid] += t;
    __syncthreads();
  }
  int ex0 = ws[tid] - psum;
  ls[2*tid]     = ex0;
  ls[2*tid + 1] = ex0 + v0;
  __syncthreads();
  for (int i = tid; i < nn; i += 256){
    int ex = beg + ls[i];
    rowp[nbase + i] = ex;
    lcur[i] = ex;
    dis[nbase + i] = rsqrtf((float)(lcnt[i] + 1));
  }
  __syncthreads();
  for (int p = beg + tid; p < endp; p += 256){
    inj_u32 w = pairs[p];
    int pos = atomicAdd(&lcur[w >> 17], 1);
    es[pos] = (int)(w & 0x1FFFFu);
  }
}

// ---- repack weights into MFMA B-fragment order, bf16 ----
// frag[ct][kk][lane][j] = W[kk*32 + (lane>>4)*8 + j][ct*16 + (lane&15)]
__global__ void inj_wfrag(const void* Wgate, const void* Wfuse,
                          const void* Wp, const void* Wg,
                          inj_u16* wfrag, inj_u16* wpf, inj_u16* wgf2,
                          const int* flags){
  int t = blockIdx.x*256 + threadIdx.x;      // [0, 11264)
  int f32 = flags[1];
  const void* W; inj_u16* dst; int kbase, n;
  if (t < 8192){
    int mat = t >> 12, r = t & 4095;
    int ct = r >> 9, kk = (r >> 6) & 7, lane = r & 63;
    W = mat ? Wfuse : Wgate;
    dst = wfrag + (size_t)mat*32768 + ((ct*8 + kk)*64 + lane)*8;
    kbase = kk*32 + (lane>>4)*8;
    n = ct*16 + (lane & 15);
  } else if (t < 9216){
    int r = t - 8192;
    int ct = r >> 7, kk = (r >> 6) & 1, lane = r & 63;
    W = Wp;
    dst = wpf + ((ct*2 + kk)*64 + lane)*8;
    kbase = kk*32 + (lane>>4)*8;
    n = ct*16 + (lane & 15);
  } else {
    int r = t - 9216;
    int ct = r >> 8, kk = (r >> 6) & 3, lane = r & 63;
    W = Wg;
    dst = wgf2 + ((ct*4 + kk)*64 + lane)*8;
    kbase = kk*32 + (lane>>4)*8;
    n = ct*16 + (lane & 15);
  }
  #pragma unroll
  for (int j=0;j<8;j++)
    dst[j] = inj_f2b(inj_ld1(W, (size_t)(kbase + j)*INJ_H + n, f32));
}

// ---- x2 = (relu(ev @ Wp + bp) @ Wg) * dis[n]  via MFMA ----
// 16 nodes/block, 4 waves. x2 written SLICE-MAJOR bf16 [8][N][16cols]
// (32B per node per slice -> one slice = 3.2MB, XCD-L2 resident).
__global__ __launch_bounds__(256) void inj_projgcn(
    const void* ev, const void* bp,
    const inj_u16* wpf, const inj_u16* wgf2,
    const float* dis, inj_u32* x2, const int* flags){
  __shared__ __align__(16) inj_u16 s_a [ 8*136];   // ev   frags (16x64)
  __shared__ __align__(16) inj_u16 s_ef[16*136];   // relu frags (16x128)
  __shared__ float s_dis[16];
  const int f32 = flags[1];
  const int tid = threadIdx.x;
  const int n0 = blockIdx.x * 16;

  if (tid < 128){
    int m = tid >> 3, g = tid & 7;                 // node, 8-col group
    uint4 v;
    if (!f32){
      v = ((const uint4*)ev)[(size_t)(n0 + m)*8 + g];
    } else {
      const float4* e4 = (const float4*)ev;
      float4 x0 = e4[(size_t)(n0 + m)*16 + g*2];
      float4 x1 = e4[(size_t)(n0 + m)*16 + g*2 + 1];
      v.x = inj_pack(x0.x, x0.y); v.y = inj_pack(x0.z, x0.w);
      v.z = inj_pack(x1.x, x1.y); v.w = inj_pack(x1.z, x1.w);
    }
    *(uint4*)(s_a + g*136 + m*8) = v;
  }
  if (tid < 16) s_dis[tid] = dis[n0 + tid];
  __syncthreads();

  const int lane = tid & 63, wave = tid >> 6;
  const int mrow = lane & 15, quad = lane >> 4;

  // GEMM1: ef = relu(ev @ Wp + bp)  (bias folded into acc init)
  float bp0 = inj_ld1(bp, (wave*2    )*16 + mrow, f32);
  float bp1 = inj_ld1(bp, (wave*2 + 1)*16 + mrow, f32);
  f32x4 acc[2] = {{bp0,bp0,bp0,bp0},{bp1,bp1,bp1,bp1}};
  #pragma unroll
  for (int kk = 0; kk < 2; kk++){
    bf16x8 a  = *(const bf16x8*)(s_a + (kk*4 + quad)*136 + mrow*8);
    bf16x8 b0 = *(const bf16x8*)(wpf + (((wave*2    )*2 + kk)*64 + lane)*8);
    bf16x8 b1 = *(const bf16x8*)(wpf + (((wave*2 + 1)*2 + kk)*64 + lane)*8);
    acc[0] = __builtin_amdgcn_mfma_f32_16x16x32_bf16(a, b0, acc[0], 0, 0, 0);
    acc[1] = __builtin_amdgcn_mfma_f32_16x16x32_bf16(a, b1, acc[1], 0, 0, 0);
  }
  #pragma unroll
  for (int t = 0; t < 2; t++){
    int col = (wave*2 + t)*16 + mrow;              // ef column = GEMM2 k
    int goff = (col >> 3)*136 + (col & 7);
    #pragma unroll
    for (int r = 0; r < 4; r++){
      int row = quad*4 + r;                        // node within tile
      s_ef[goff + row*8] = inj_f2b(fmaxf(acc[t][r], 0.f));
    }
  }
  __syncthreads();

  // GEMM2: x2 = (ef @ Wg) * dis  (b_gcn + relu applied in gather)
  f32x4 acc2[2] = {{0.f,0.f,0.f,0.f},{0.f,0.f,0.f,0.f}};
  #pragma unroll
  for (int kk = 0; kk < 4; kk++){
    bf16x8 a  = *(const bf16x8*)(s_ef + (kk*4 + quad)*136 + mrow*8);
    bf16x8 b0 = *(const bf16x8*)(wgf2 + (((wave*2    )*4 + kk)*64 + lane)*8);
    bf16x8 b1 = *(const bf16x8*)(wgf2 + (((wave*2 + 1)*4 + kk)*64 + lane)*8);
    acc2[0] = __builtin_amdgcn_mfma_f32_16x16x32_bf16(a, b0, acc2[0], 0, 0, 0);
    acc2[1] = __builtin_amdgcn_mfma_f32_16x16x32_bf16(a, b1, acc2[1], 0, 0, 0);
  }
  inj_u16* xo = (inj_u16*)x2;
  #pragma unroll
  for (int t = 0; t < 2; t++){
    int col = (wave*2 + t)*16 + mrow;
    int slice = col >> 4;                          // = wave*2 + t
    #pragma unroll
    for (int r = 0; r < 4; r++){
      int row = quad*4 + r;
      xo[((size_t)slice*INJ_N + (n0 + row))*16 + (col & 15)] =
          inj_f2b(acc2[t][r] * s_dis[row]);
    }
  }
}

// ---- sliced gather: slice = blockIdx&7 (XCD affinity via round-robin) ----
// 2048 blocks = 8/CU, all co-resident (no LDS, low VGPR). Wave: 8 source-
// groups x 8 lanes; lane reads one u32 (2 cols) of its group's source row
// from the 3.2MB L2-resident slice. Cross-group shfl_xor reduce; self term
// added ONCE in group 0 post-reduction (R20 fix). es/dif nontemporal.
__global__ __launch_bounds__(256, 8) void inj_gather(
    const inj_u32* x2, const int* rowp, const int* es,
    const float* dis, const void* bgcn, inj_u32* dif, const int* flags){
  const int tid = threadIdx.x;
  const int lane = tid & 63, wv = tid >> 6;
  const int s = blockIdx.x & 7;                    // feature slice
  const int g = lane >> 3, c = lane & 7;           // source group, col pair
  const inj_u32* xs = x2 + (size_t)s * INJ_N * 8;
  float2 bg = inj_ld2(bgcn, (size_t)(s*8 + c), flags[1]);
  const int wbase = (blockIdx.x >> 3)*4 + wv;      // [0, 1024)
  const int wstr  = (int)(gridDim.x >> 3)*4;       // 1024
  for (int n = wbase; n < INJ_N; n += wstr){
    const float dd = dis[n];
    inj_u32 xv = xs[(size_t)n*8 + c];              // self term (pre-scaled)
    float a0 = 0.f, a1 = 0.f;
    const int beg = rowp[n], end = rowp[n+1];
    int k = beg;
    for (; k + 16 <= end; k += 16){
      int s0 = __builtin_nontemporal_load(es + k + g);
      int s1 = __builtin_nontemporal_load(es + k + 8 + g);
      inj_u32 v0 = xs[(size_t)s0*8 + c];
      inj_u32 v1 = xs[(size_t)s1*8 + c];
      a0 += inj_lo(v0) + inj_lo(v1);
      a1 += inj_hi(v0) + inj_hi(v1);
    }
    for (; k + 8 <= end; k += 8){
      int s0 = __builtin_nontemporal_load(es + k + g);
      inj_u32 v0 = xs[(size_t)s0*8 + c];
      a0 += inj_lo(v0);
      a1 += inj_hi(v0);
    }
    if (k < end && g < end - k){
      int s0 = __builtin_nontemporal_load(es + k + g);
      inj_u32 v0 = xs[(size_t)s0*8 + c];
      a0 += inj_lo(v0);
      a1 += inj_hi(v0);
    }
    // reduce across the 8 groups (lane bits 3..5)
    a0 += __shfl_xor(a0, 8);  a1 += __shfl_xor(a1, 8);
    a0 += __shfl_xor(a0, 16); a1 += __shfl_xor(a1, 16);
    a0 += __shfl_xor(a0, 32); a1 += __shfl_xor(a1, 32);
    if (g == 0){
      a0 += inj_lo(xv);                            // self term, once
      a1 += inj_hi(xv);
      float r0 = fmaxf(fmaf(a0, dd, bg.x), 0.f);
      float r1 = fmaxf(fmaf(a1, dd, bg.y), 0.f);
      __builtin_nontemporal_store(inj_pack(r0, r1), dif + (size_t)n*64 + s*8 + c);
    }
  }
}

// ---- MFMA epilogue (R13 form): gate -> blend -> fuse -> out ----
// 16 nodes/block, 4 waves; wave w covers cols [32w, 32w+32) (2 col-tiles).
// A-operands in LDS fragment order: elem(m, k) at [g*136 + m*8 + (k&7)],
// g = (k>>5)*4 + ((k>>3)&3).
__global__ __launch_bounds__(256) void InjectionLayer_91130616086689_kernel(
    const void* base, const void* bgate, const void* bfuse,
    const inj_u16* wgf, const inj_u16* wff,
    const inj_u32* dif, void* outp, const int* flags){
  __shared__ __align__(16) inj_u16 s_b[16*136];   // base  frags (4352 B)
  __shared__ __align__(16) inj_u16 s_d[16*136];   // dif   frags
  __shared__ __align__(16) inj_u16 s_c[16*136];   // corrected frags
  const int f32 = flags[1];
  const int tid = threadIdx.x;
  const int n0 = blockIdx.x * 16;

  // ---- stage base + dif into fragment-order LDS ----
  {
    int m = tid >> 4, g = tid & 15;               // node, 8-col group
    uint4 vb;
    if (!f32){
      vb = ((const uint4*)base)[(size_t)(n0 + m)*16 + g];
    } else {
      const float4* b4 = (const float4*)base;
      float4 x0 = b4[(size_t)(n0 + m)*32 + g*2];
      float4 x1 = b4[(size_t)(n0 + m)*32 + g*2 + 1];
      vb.x = inj_pack(x0.x, x0.y); vb.y = inj_pack(x0.z, x0.w);
      vb.z = inj_pack(x1.x, x1.y); vb.w = inj_pack(x1.z, x1.w);
    }
    *(uint4*)(s_b + g*136 + m*8) = vb;
    uint4 vd = ((const uint4*)dif)[(size_t)(n0 + m)*16 + g];
    *(uint4*)(s_d + g*136 + m*8) = vd;
  }
  __syncthreads();

  const int lane = tid & 63, wave = tid >> 6;
  const int mrow = lane & 15, quad = lane >> 4;

  // ---- GEMM1: gate_pre = [base|dif] @ Wgate ----
  f32x4 accg[2] = {{0.f,0.f,0.f,0.f},{0.f,0.f,0.f,0.f}};
  #pragma unroll
  for (int kk = 0; kk < 8; kk++){
    const inj_u16* mat = (kk < 4) ? s_b : s_d;
    int g = (kk & 3)*4 + quad;
    bf16x8 a = *(const bf16x8*)(mat + g*136 + mrow*8);
    bf16x8 b0 = *(const bf16x8*)(wgf + (((wave*2    )*8 + kk)*64 + lane)*8);
    bf16x8 b1 = *(const bf16x8*)(wgf + (((wave*2 + 1)*8 + kk)*64 + lane)*8);
    accg[0] = __builtin_amdgcn_mfma_f32_16x16x32_bf16(a, b0, accg[0], 0, 0, 0);
    accg[1] = __builtin_amdgcn_mfma_f32_16x16x32_bf16(a, b1, accg[1], 0, 0, 0);
  }

  // ---- sigmoid + blend -> corrected frags ----
  #pragma unroll
  for (int t = 0; t < 2; t++){
    int col = (wave*2 + t)*16 + mrow;
    float bg = inj_ld1(bgate, col, f32);
    int gk = (col >> 5)*4 + ((col >> 3) & 3), jj = col & 7;
    #pragma unroll
    for (int r = 0; r < 4; r++){
      int row = quad*4 + r;
      float gate = 1.f/(1.f + expf(-(accg[t][r] + bg)));
      int off = gk*136 + row*8 + jj;
      float bb = inj_b2f(s_b[off]);
      float dd = inj_b2f(s_d[off]);
      s_c[off] = inj_f2b(bb*(1.f - gate) + dd*gate);
    }
  }
  __syncthreads();

  // ---- GEMM2: out = relu([base|corrected] @ Wfuse + b) ----
  f32x4 accf[2] = {{0.f,0.f,0.f,0.f},{0.f,0.f,0.f,0.f}};
  #pragma unroll
  for (int kk = 0; kk < 8; kk++){
    const inj_u16* mat = (kk < 4) ? s_b : s_c;
    int g = (kk & 3)*4 + quad;
    bf16x8 a = *(const bf16x8*)(mat + g*136 + mrow*8);
    bf16x8 b0 = *(const bf16x8*)(wff + (((wave*2    )*8 + kk)*64 + lane)*8);
    bf16x8 b1 = *(const bf16x8*)(wff + (((wave*2 + 1)*8 + kk)*64 + lane)*8);
    accf[0] = __builtin_amdgcn_mfma_f32_16x16x32_bf16(a, b0, accf[0], 0, 0, 0);
    accf[1] = __builtin_amdgcn_mfma_f32_16x16x32_bf16(a, b1, accf[1], 0, 0, 0);
  }
  #pragma unroll
  for (int t = 0; t < 2; t++){
    int col = (wave*2 + t)*16 + mrow;
    float bf = inj_ld1(bfuse, col, f32);
    #pragma unroll
    for (int r = 0; r < 4; r++){
      int row = quad*4 + r;
      float v = fmaxf(accf[t][r] + bf, 0.f);
      size_t oi = (size_t)(n0 + row)*INJ_H + col;
      if (f32) ((float*)outp)[oi] = v;
      else     ((inj_u16*)outp)[oi] = inj_f2b(v);
    }
  }
}

extern "C" __attribute__((visibility("default")))
void kernel_launch(void* const* d_in, const int* in_sizes, int n_in,
                   void* d_out, int out_size, void* d_ws, size_t ws_size,
                   hipStream_t stream) {
  const void* base  = d_in[0];
  const void* ev    = d_in[1];
  const int*  eidx  = (const int*)d_in[2];
  const void* Wp    = d_in[3];
  const void* bp    = d_in[4];
  const void* Wg    = d_in[5];
  const void* bg    = d_in[6];
  const void* Wgate = d_in[7];
  const void* bgate = d_in[8];
  const void* Wfuse = d_in[9];
  const void* bfuse = d_in[10];

  // x2 (sliced bf16 [8][N][16]) staged in d_out; fully consumed by the
  // gather before the epilogue overwrites d_out (R13 pattern).
  inj_u32* x2 = (inj_u32*)d_out;

  char* ws = (char*)d_ws;
  inj_u32* dif    = (inj_u32*)(ws);                 // 25,600,000 B
  inj_u32* pairs  = (inj_u32*)(ws);                 //  6,400,000 B (dif head;
                                                    //  dead before gather)
  int*     es     = (int*)    (ws + 25600000);      //  6,400,000 B
  int*     bhp    = (int*)    (ws + 32000000);      //     12,544 B (64B-padded)
  inj_u16* wpf    = (inj_u16*)(ws + 32016384);      //     16,384 B
  inj_u16* wgf2   = (inj_u16*)(ws + 32032768);      //     32,768 B
  int*     bbase  = (int*)    (ws + 32065536);      //        788 B
  int*     rowp   = (int*)    (ws + 32400000);      //    400,004 B
  int*     bcurA  = (int*)    (ws + 32800016);      //     12,544 B (64B-padded)
  float*   dis    = (float*)  (ws + 33200016);      //    400,000 B
  int*     flags  = (int*)    (ws + 33601600);      //          8 B
  inj_u16* wfrag  = (inj_u16*)(ws + 33601664);      //    131,072 B (wgf|wff)

  hipMemsetAsync(bhp, 0, (size_t)INJ_NB*64, stream);
  inj_flags  <<<1, 64, 0, stream>>>(eidx, (const inj_u32*)base, flags);
  inj_bhist  <<<INJ_PB, 256, 0, stream>>>(eidx, bhp, flags);
  inj_wfrag  <<<44, 256, 0, stream>>>(Wgate, Wfuse, Wp, Wg, wfrag, wpf, wgf2, flags);
  inj_bscan  <<<1, 256, 0, stream>>>(bhp, bbase, bcurA, rowp);
  inj_passA  <<<INJ_PB, 256, 0, stream>>>(eidx, bcurA, pairs, flags);
  inj_passB  <<<INJ_NB, 256, 0, stream>>>(pairs, bbase, rowp, dis, es);
  inj_projgcn<<<INJ_N/16, 256, 0, stream>>>(ev, bp, wpf, wgf2, dis, x2, flags);
  inj_gather <<<2048, 256, 0, stream>>>(x2, rowp, es, dis, bg, dif, flags);
  InjectionLayer_91130616086689_kernel<<<INJ_N/16, 256, 0, stream>>>(
      base, bgate, bfuse, wfrag, wfrag + 32768, dif, d_out, flags);
}

// Round 13
// 307.793 us; speedup vs baseline: 1.5353x; 1.5353x over previous
//
#include <hip/hip_runtime.h>

// InjectionLayer: event proj + GCNConv diffusion + gated fuse.
// N=100000, E=1600000, EVENT_DIM=64, HID=128.
// R9: projgcn via MFMA with pre-repacked fragments (706->511us).
// R10: bucketed counting-sort CSR build (511->490us).
// R11: gather pre-scaled x + 8-deep MLP unroll (490->441us).
// R12/R13: chunked run-reservation passA, LDS bhist (441->318us).
// R14: gather fused into MFMA epilogue (318->310us).  <-- BEST (310.4us)
// R17: 16-deep MLP null (TLP-limited, not ILP). R18: 128-thr reshape
//      regressed (occupancy fell). R20: feature-sliced gather cut L2-miss
//      traffic 190->59MB but became latency-bound (220us): per-node
//      dependent chains, 8x node-visit duplication.
// R21: RESTORE R14 verbatim -- all measured avenues (ILP/TLP/traffic)
//      confirm the fused structure sits at the random-access fabric
//      ceiling (~3.5TB/s gather phase, L3-served).

typedef unsigned short inj_u16;
typedef unsigned int   inj_u32;
typedef __attribute__((ext_vector_type(8))) short bf16x8;
typedef __attribute__((ext_vector_type(4))) float f32x4;

static constexpr int INJ_N  = 100000;
static constexpr int INJ_E  = 1600000;
static constexpr int INJ_H  = 128;
static constexpr int INJ_D  = 64;
static constexpr int INJ_NB = 196;   // ceil(N/512) buckets of 512 nodes
static constexpr int INJ_CH = 6400;  // edges per passA/bhist block
static constexpr int INJ_PB = 250;   // chunk blocks = E/6400

__device__ __forceinline__ float inj_b2f(inj_u16 h){
  union { inj_u32 u; float f; } c; c.u = ((inj_u32)h) << 16; return c.f;
}
__device__ __forceinline__ inj_u16 inj_f2b(float x){
  union { inj_u32 u; float f; } c; c.f = x;
  return (inj_u16)((c.u + 0x7FFFu + ((c.u >> 16) & 1u)) >> 16);
}
__device__ __forceinline__ float inj_lo(inj_u32 w){ return inj_b2f((inj_u16)(w & 0xFFFFu)); }
__device__ __forceinline__ float inj_hi(inj_u32 w){ return inj_b2f((inj_u16)(w >> 16)); }
__device__ __forceinline__ inj_u32 inj_pack(float a, float b){
  return ((inj_u32)inj_f2b(b) << 16) | (inj_u32)inj_f2b(a);
}
__device__ __forceinline__ float inj_ld1(const void* p, size_t i, int f32){
  return f32 ? ((const float*)p)[i] : inj_b2f(((const inj_u16*)p)[i]);
}
__device__ __forceinline__ float2 inj_ld2(const void* p, size_t pair, int f32){
  if (f32) return ((const float2*)p)[pair];
  inj_u32 w = ((const inj_u32*)p)[pair];
  float2 r; r.x = inj_lo(w); r.y = inj_hi(w);
  return r;
}

// ---- runtime format probes ----
__global__ void inj_flags(const int* eidx, const inj_u32* base, int* flags){
  int l = threadIdx.x & 63;
  unsigned long long nz = __ballot(eidx[2*l + 1] != 0);
  inj_u32 ex = (base[l] >> 7) & 0xFFu;
  unsigned long long inr = __ballot(ex >= 100u && ex <= 135u);
  if (threadIdx.x == 0){
    flags[0] = (nz == 0ull) ? 1 : 0;              // int64 edges?
    flags[1] = (__popcll(inr) >= 56) ? 0 : 1;     // 0 = bf16, 1 = f32
  }
}

__device__ __forceinline__ int inj_eread(const int* e, size_t i, int w64){
  return w64 ? e[2*i] : e[i];
}

// ---- bucket histogram: LDS per-block hist -> 196 global atomics/block ----
__global__ __launch_bounds__(256) void inj_bhist(const int* eidx, int* bhp,
                                                 const int* flags){
  __shared__ int h[INJ_NB];
  const int tid = threadIdx.x;
  const int e0 = blockIdx.x * INJ_CH;
  const int w64 = flags[0];
  for (int b = tid; b < INJ_NB; b += 256) h[b] = 0;
  __syncthreads();
  for (int i = tid; i < INJ_CH; i += 256){
    int dst = inj_eread(eidx, (size_t)INJ_E + e0 + i, w64);
    atomicAdd(&h[dst >> 9], 1);
  }
  __syncthreads();
  for (int b = tid; b < INJ_NB; b += 256)
    if (h[b]) atomicAdd(&bhp[b*16], h[b]);
}

// ---- scan bucket counts -> bucket bases + passA cursors ----
__global__ void inj_bscan(const int* bhp, int* bbase, int* bcurA, int* rowp){
  __shared__ int s[256];
  int tid = threadIdx.x;
  int v = (tid < INJ_NB) ? bhp[tid*16] : 0;
  s[tid] = v; __syncthreads();
  for (int off = 1; off < 256; off <<= 1){
    int t = (tid >= off) ? s[tid - off] : 0;
    __syncthreads();
    s[tid] += t;
    __syncthreads();
  }
  if (tid < INJ_NB){
    int base = s[tid] - v;          // exclusive prefix
    bbase[tid]    = base;
    bcurA[tid*16] = base;
  }
  if (tid == 0){ bbase[INJ_NB] = INJ_E; rowp[INJ_N] = INJ_E; }
}

// ---- pass A: chunked run-reservation scatter ----
__global__ __launch_bounds__(256) void inj_passA(
    const int* eidx, int* bcurA, inj_u32* pairs, const int* flags){
  __shared__ inj_u32 sedge[INJ_CH];
  __shared__ unsigned char sbkt[INJ_CH];
  __shared__ int scnt[INJ_NB];
  __shared__ int scur[INJ_NB];
  const int tid = threadIdx.x;
  const int e0 = blockIdx.x * INJ_CH;
  const int w64 = flags[0];
  for (int b = tid; b < INJ_NB; b += 256) scnt[b] = 0;
  __syncthreads();
  for (int i = tid; i < INJ_CH; i += 256){
    int src = inj_eread(eidx, (size_t)(e0 + i), w64);
    int dst = inj_eread(eidx, (size_t)INJ_E + e0 + i, w64);
    int b = dst >> 9;
    sedge[i] = (inj_u32)src | ((inj_u32)(dst & 511) << 17);
    sbkt[i] = (unsigned char)b;
    atomicAdd(&scnt[b], 1);
  }
  __syncthreads();
  for (int b = tid; b < INJ_NB; b += 256){
    int c = scnt[b];
    scur[b] = c ? atomicAdd(&bcurA[b*16], c) : 0;
  }
  __syncthreads();
  for (int i = tid; i < INJ_CH; i += 256){
    int b = sbkt[i];
    int pos = atomicAdd(&scur[b], 1);
    pairs[pos] = sedge[i];
  }
}

// ---- pass B: per 512-node bucket -- LDS count/scan -> rowp/dis, fill ----
__global__ __launch_bounds__(256) void inj_passB(
    const inj_u32* pairs, const int* bbase, int* rowp, float* dis, int* es){
  __shared__ int lcnt[512];
  __shared__ int lcur[512];
  __shared__ int ls[512];
  __shared__ int ws[256];
  const int b = blockIdx.x, tid = threadIdx.x;
  const int beg = bbase[b], endp = bbase[b+1];
  const int nbase = b << 9;
  const int nn = min(512, INJ_N - nbase);
  for (int i = tid; i < 512; i += 256) lcnt[i] = 0;
  __syncthreads();
  for (int p = beg + tid; p < endp; p += 256)
    atomicAdd(&lcnt[pairs[p] >> 17], 1);
  __syncthreads();
  // scan 512: 2 consecutive elems per thread, block-scan the pair sums
  int v0 = lcnt[2*tid], v1 = lcnt[2*tid + 1];
  int psum = v0 + v1;
  ws[tid] = psum; __syncthreads();
  for (int off = 1; off < 256; off <<= 1){
    int t = (tid >= off) ? ws[tid - off] : 0;
    __syncthreads();
    ws[tid] += t;
    __syncthreads();
  }
  int ex0 = ws[tid] - psum;
  ls[2*tid]     = ex0;
  ls[2*tid + 1] = ex0 + v0;
  __syncthreads();
  for (int i = tid; i < nn; i += 256){
    int ex = beg + ls[i];
    rowp[nbase + i] = ex;
    lcur[i] = ex;
    dis[nbase + i] = rsqrtf((float)(lcnt[i] + 1));
  }
  __syncthreads();
  for (int p = beg + tid; p < endp; p += 256){
    inj_u32 w = pairs[p];
    int pos = atomicAdd(&lcur[w >> 17], 1);
    es[pos] = (int)(w & 0x1FFFFu);
  }
}

// ---- repack weights into MFMA B-fragment order, bf16 ----
// frag[ct][kk][lane][j] = W[kk*32 + (lane>>4)*8 + j][ct*16 + (lane&15)]
__global__ void inj_wfrag(const void* Wgate, const void* Wfuse,
                          const void* Wp, const void* Wg,
                          inj_u16* wfrag, inj_u16* wpf, inj_u16* wgf2,
                          const int* flags){
  int t = blockIdx.x*256 + threadIdx.x;      // [0, 11264)
  int f32 = flags[1];
  const void* W; inj_u16* dst; int kbase, n;
  if (t < 8192){
    int mat = t >> 12, r = t & 4095;
    int ct = r >> 9, kk = (r >> 6) & 7, lane = r & 63;
    W = mat ? Wfuse : Wgate;
    dst = wfrag + (size_t)mat*32768 + ((ct*8 + kk)*64 + lane)*8;
    kbase = kk*32 + (lane>>4)*8;
    n = ct*16 + (lane & 15);
  } else if (t < 9216){
    int r = t - 8192;
    int ct = r >> 7, kk = (r >> 6) & 1, lane = r & 63;
    W = Wp;
    dst = wpf + ((ct*2 + kk)*64 + lane)*8;
    kbase = kk*32 + (lane>>4)*8;
    n = ct*16 + (lane & 15);
  } else {
    int r = t - 9216;
    int ct = r >> 8, kk = (r >> 6) & 3, lane = r & 63;
    W = Wg;
    dst = wgf2 + ((ct*4 + kk)*64 + lane)*8;
    kbase = kk*32 + (lane>>4)*8;
    n = ct*16 + (lane & 15);
  }
  #pragma unroll
  for (int j=0;j<8;j++)
    dst[j] = inj_f2b(inj_ld1(W, (size_t)(kbase + j)*INJ_H + n, f32));
}

// ---- x = (relu(ev @ Wp + bp) @ Wg) * dis[n]  via MFMA ----
// 16 nodes/block, 4 waves. x written row-major bf16 [N][128] to WORKSPACE,
// pre-scaled by dis[n].
__global__ __launch_bounds__(256) void inj_projgcn(
    const void* ev, const void* bp,
    const inj_u16* wpf, const inj_u16* wgf2,
    const float* dis, inj_u32* x, const int* flags){
  __shared__ __align__(16) inj_u16 s_a [ 8*136];   // ev   frags (16x64)
  __shared__ __align__(16) inj_u16 s_ef[16*136];   // relu frags (16x128)
  __shared__ float s_dis[16];
  const int f32 = flags[1];
  const int tid = threadIdx.x;
  const int n0 = blockIdx.x * 16;

  if (tid < 128){
    int m = tid >> 3, g = tid & 7;                 // node, 8-col group
    uint4 v;
    if (!f32){
      v = ((const uint4*)ev)[(size_t)(n0 + m)*8 + g];
    } else {
      const float4* e4 = (const float4*)ev;
      float4 x0 = e4[(size_t)(n0 + m)*16 + g*2];
      float4 x1 = e4[(size_t)(n0 + m)*16 + g*2 + 1];
      v.x = inj_pack(x0.x, x0.y); v.y = inj_pack(x0.z, x0.w);
      v.z = inj_pack(x1.x, x1.y); v.w = inj_pack(x1.z, x1.w);
    }
    *(uint4*)(s_a + g*136 + m*8) = v;
  }
  if (tid < 16) s_dis[tid] = dis[n0 + tid];
  __syncthreads();

  const int lane = tid & 63, wave = tid >> 6;
  const int mrow = lane & 15, quad = lane >> 4;

  // GEMM1: ef = relu(ev @ Wp + bp)  (bias folded into acc init)
  float bp0 = inj_ld1(bp, (wave*2    )*16 + mrow, f32);
  float bp1 = inj_ld1(bp, (wave*2 + 1)*16 + mrow, f32);
  f32x4 acc[2] = {{bp0,bp0,bp0,bp0},{bp1,bp1,bp1,bp1}};
  #pragma unroll
  for (int kk = 0; kk < 2; kk++){
    bf16x8 a  = *(const bf16x8*)(s_a + (kk*4 + quad)*136 + mrow*8);
    bf16x8 b0 = *(const bf16x8*)(wpf + (((wave*2    )*2 + kk)*64 + lane)*8);
    bf16x8 b1 = *(const bf16x8*)(wpf + (((wave*2 + 1)*2 + kk)*64 + lane)*8);
    acc[0] = __builtin_amdgcn_mfma_f32_16x16x32_bf16(a, b0, acc[0], 0, 0, 0);
    acc[1] = __builtin_amdgcn_mfma_f32_16x16x32_bf16(a, b1, acc[1], 0, 0, 0);
  }
  #pragma unroll
  for (int t = 0; t < 2; t++){
    int col = (wave*2 + t)*16 + mrow;              // ef column = GEMM2 k
    int goff = (col >> 3)*136 + (col & 7);
    #pragma unroll
    for (int r = 0; r < 4; r++){
      int row = quad*4 + r;                        // node within tile
      s_ef[goff + row*8] = inj_f2b(fmaxf(acc[t][r], 0.f));
    }
  }
  __syncthreads();

  // GEMM2: x = (ef @ Wg) * dis  (b_gcn + relu applied in fused gather)
  f32x4 acc2[2] = {{0.f,0.f,0.f,0.f},{0.f,0.f,0.f,0.f}};
  #pragma unroll
  for (int kk = 0; kk < 4; kk++){
    bf16x8 a  = *(const bf16x8*)(s_ef + (kk*4 + quad)*136 + mrow*8);
    bf16x8 b0 = *(const bf16x8*)(wgf2 + (((wave*2    )*4 + kk)*64 + lane)*8);
    bf16x8 b1 = *(const bf16x8*)(wgf2 + (((wave*2 + 1)*4 + kk)*64 + lane)*8);
    acc2[0] = __builtin_amdgcn_mfma_f32_16x16x32_bf16(a, b0, acc2[0], 0, 0, 0);
    acc2[1] = __builtin_amdgcn_mfma_f32_16x16x32_bf16(a, b1, acc2[1], 0, 0, 0);
  }
  inj_u16* xo = (inj_u16*)x;
  #pragma unroll
  for (int t = 0; t < 2; t++){
    int col = (wave*2 + t)*16 + mrow;
    #pragma unroll
    for (int r = 0; r < 4; r++){
      int row = quad*4 + r;
      xo[(size_t)(n0 + row)*INJ_H + col] = inj_f2b(acc2[t][r] * s_dis[row]);
    }
  }
}

// ---- fused gather + MFMA epilogue: one launch, 16 nodes/block ----
// Phase 1: stage base frags; wave wv gathers its 4 nodes' CSR rows
//   (8-deep MLP unroll) and writes dif = relu(dd*sum + b) DIRECTLY into
//   s_d fragment order (lane owns cols 2l,2l+1 -> one aligned u32 store).
// Phase 2 (after one barrier): GEMM1 -> sigmoid/blend -> GEMM2 -> out.
__global__ __launch_bounds__(256) void InjectionLayer_91130616086689_kernel(
    const void* base, const void* bgate, const void* bfuse,
    const inj_u16* wgf, const inj_u16* wff,
    const inj_u32* x, const int* rowp, const int* es, const float* dis,
    const void* bgcn, void* outp, const int* flags){
  __shared__ __align__(16) inj_u16 s_b[16*136];   // base  frags (4352 B)
  __shared__ __align__(16) inj_u16 s_d[16*136];   // dif   frags
  __shared__ __align__(16) inj_u16 s_c[16*136];   // corrected frags
  const int f32 = flags[1];
  const int tid = threadIdx.x;
  const int n0 = blockIdx.x * 16;
  const int lane = tid & 63, wave = tid >> 6;

  // ---- stage base into fragment-order LDS (latency hides under gather) ----
  {
    int m = tid >> 4, g = tid & 15;               // node, 8-col group
    uint4 vb;
    if (!f32){
      vb = ((const uint4*)base)[(size_t)(n0 + m)*16 + g];
    } else {
      const float4* b4 = (const float4*)base;
      float4 x0 = b4[(size_t)(n0 + m)*32 + g*2];
      float4 x1 = b4[(size_t)(n0 + m)*32 + g*2 + 1];
      vb.x = inj_pack(x0.x, x0.y); vb.y = inj_pack(x0.z, x0.w);
      vb.z = inj_pack(x1.x, x1.y); vb.w = inj_pack(x1.z, x1.w);
    }
    *(uint4*)(s_b + g*136 + m*8) = vb;
  }

  // ---- gather phase: wave wv handles nodes wv*4 .. wv*4+3 ----
  {
    float2 bg = inj_ld2(bgcn, lane, f32);
    const int doff = (lane >> 2)*136 + ((2*lane) & 7);  // frag offset base
    for (int t = 0; t < 4; t++){
      const int m = wave*4 + t;
      const int n = n0 + m;
      const float dd = dis[n];
      inj_u32 xv = x[(size_t)n*64 + lane];
      float a0 = inj_lo(xv), a1 = inj_hi(xv);
      const int beg = rowp[n], end = rowp[n+1];
      for (int c = beg; c < end; c += 64){
        int mm = end - c; if (mm > 64) mm = 64;
        int srcv = (lane < mm) ? es[c + lane] : 0;
        int j = 0;
        for (; j + 8 <= mm; j += 8){
          int s0 = __shfl(srcv, j  ), s1 = __shfl(srcv, j+1);
          int s2 = __shfl(srcv, j+2), s3 = __shfl(srcv, j+3);
          int s4 = __shfl(srcv, j+4), s5 = __shfl(srcv, j+5);
          int s6 = __shfl(srcv, j+6), s7 = __shfl(srcv, j+7);
          inj_u32 v0 = x[(size_t)s0*64 + lane];
          inj_u32 v1 = x[(size_t)s1*64 + lane];
          inj_u32 v2 = x[(size_t)s2*64 + lane];
          inj_u32 v3 = x[(size_t)s3*64 + lane];
          inj_u32 v4 = x[(size_t)s4*64 + lane];
          inj_u32 v5 = x[(size_t)s5*64 + lane];
          inj_u32 v6 = x[(size_t)s6*64 + lane];
          inj_u32 v7 = x[(size_t)s7*64 + lane];
          a0 += inj_lo(v0) + inj_lo(v1) + inj_lo(v2) + inj_lo(v3)
              + inj_lo(v4) + inj_lo(v5) + inj_lo(v6) + inj_lo(v7);
          a1 += inj_hi(v0) + inj_hi(v1) + inj_hi(v2) + inj_hi(v3)
              + inj_hi(v4) + inj_hi(v5) + inj_hi(v6) + inj_hi(v7);
        }
        for (; j + 4 <= mm; j += 4){
          int s0 = __shfl(srcv, j  ), s1 = __shfl(srcv, j+1);
          int s2 = __shfl(srcv, j+2), s3 = __shfl(srcv, j+3);
          inj_u32 v0 = x[(size_t)s0*64 + lane];
          inj_u32 v1 = x[(size_t)s1*64 + lane];
          inj_u32 v2 = x[(size_t)s2*64 + lane];
          inj_u32 v3 = x[(size_t)s3*64 + lane];
          a0 += inj_lo(v0) + inj_lo(v1) + inj_lo(v2) + inj_lo(v3);
          a1 += inj_hi(v0) + inj_hi(v1) + inj_hi(v2) + inj_hi(v3);
        }
        for (; j < mm; ++j){
          inj_u32 v = x[(size_t)__shfl(srcv, j)*64 + lane];
          a0 += inj_lo(v);
          a1 += inj_hi(v);
        }
      }
      a0 = fmaxf(fmaf(a0, dd, bg.x), 0.f);
      a1 = fmaxf(fmaf(a1, dd, bg.y), 0.f);
      *(inj_u32*)(s_d + doff + m*8) = inj_pack(a0, a1);
    }
  }
  __syncthreads();

  const int mrow = lane & 15, quad = lane >> 4;

  // ---- GEMM1: gate_pre = [base|dif] @ Wgate ----
  f32x4 accg[2] = {{0.f,0.f,0.f,0.f},{0.f,0.f,0.f,0.f}};
  #pragma unroll
  for (int kk = 0; kk < 8; kk++){
    const inj_u16* mat = (kk < 4) ? s_b : s_d;
    int g = (kk & 3)*4 + quad;
    bf16x8 a = *(const bf16x8*)(mat + g*136 + mrow*8);
    bf16x8 b0 = *(const bf16x8*)(wgf + (((wave*2    )*8 + kk)*64 + lane)*8);
    bf16x8 b1 = *(const bf16x8*)(wgf + (((wave*2 + 1)*8 + kk)*64 + lane)*8);
    accg[0] = __builtin_amdgcn_mfma_f32_16x16x32_bf16(a, b0, accg[0], 0, 0, 0);
    accg[1] = __builtin_amdgcn_mfma_f32_16x16x32_bf16(a, b1, accg[1], 0, 0, 0);
  }

  // ---- sigmoid + blend -> corrected frags ----
  #pragma unroll
  for (int t = 0; t < 2; t++){
    int col = (wave*2 + t)*16 + mrow;
    float bg = inj_ld1(bgate, col, f32);
    int gk = (col >> 5)*4 + ((col >> 3) & 3), jj = col & 7;
    #pragma unroll
    for (int r = 0; r < 4; r++){
      int row = quad*4 + r;
      float gate = 1.f/(1.f + expf(-(accg[t][r] + bg)));
      int off = gk*136 + row*8 + jj;
      float bb = inj_b2f(s_b[off]);
      float dd = inj_b2f(s_d[off]);
      s_c[off] = inj_f2b(bb*(1.f - gate) + dd*gate);
    }
  }
  __syncthreads();

  // ---- GEMM2: out = relu([base|corrected] @ Wfuse + b) ----
  f32x4 accf[2] = {{0.f,0.f,0.f,0.f},{0.f,0.f,0.f,0.f}};
  #pragma unroll
  for (int kk = 0; kk < 8; kk++){
    const inj_u16* mat = (kk < 4) ? s_b : s_c;
    int g = (kk & 3)*4 + quad;
    bf16x8 a = *(const bf16x8*)(mat + g*136 + mrow*8);
    bf16x8 b0 = *(const bf16x8*)(wff + (((wave*2    )*8 + kk)*64 + lane)*8);
    bf16x8 b1 = *(const bf16x8*)(wff + (((wave*2 + 1)*8 + kk)*64 + lane)*8);
    accf[0] = __builtin_amdgcn_mfma_f32_16x16x32_bf16(a, b0, accf[0], 0, 0, 0);
    accf[1] = __builtin_amdgcn_mfma_f32_16x16x32_bf16(a, b1, accf[1], 0, 0, 0);
  }
  #pragma unroll
  for (int t = 0; t < 2; t++){
    int col = (wave*2 + t)*16 + mrow;
    float bf = inj_ld1(bfuse, col, f32);
    #pragma unroll
    for (int r = 0; r < 4; r++){
      int row = quad*4 + r;
      float v = fmaxf(accf[t][r] + bf, 0.f);
      size_t oi = (size_t)(n0 + row)*INJ_H + col;
      if (f32) ((float*)outp)[oi] = v;
      else     ((inj_u16*)outp)[oi] = inj_f2b(v);
    }
  }
}

extern "C" __attribute__((visibility("default")))
void kernel_launch(void* const* d_in, const int* in_sizes, int n_in,
                   void* d_out, int out_size, void* d_ws, size_t ws_size,
                   hipStream_t stream) {
  const void* base  = d_in[0];
  const void* ev    = d_in[1];
  const int*  eidx  = (const int*)d_in[2];
  const void* Wp    = d_in[3];
  const void* bp    = d_in[4];
  const void* Wg    = d_in[5];
  const void* bg    = d_in[6];
  const void* Wgate = d_in[7];
  const void* bgate = d_in[8];
  const void* Wfuse = d_in[9];
  const void* bfuse = d_in[10];

  char* ws = (char*)d_ws;
  // x (bf16 [N][128], pre-scaled) lives at ws head. pairs overlaps it:
  // passB consumes pairs strictly before projgcn writes x (stream order).
  inj_u32* x      = (inj_u32*)(ws);                 // 25,600,000 B
  inj_u32* pairs  = (inj_u32*)(ws);                 //  6,400,000 B (x head)
  int*     es     = (int*)    (ws + 25600000);      //  6,400,000 B
  int*     bhp    = (int*)    (ws + 32000000);      //     12,544 B (64B-padded)
  inj_u16* wpf    = (inj_u16*)(ws + 32016384);      //     16,384 B
  inj_u16* wgf2   = (inj_u16*)(ws + 32032768);      //     32,768 B
  int*     bbase  = (int*)    (ws + 32065536);      //        788 B
  int*     rowp   = (int*)    (ws + 32400000);      //    400,004 B
  int*     bcurA  = (int*)    (ws + 32800016);      //     12,544 B (64B-padded)
  float*   dis    = (float*)  (ws + 33200016);      //    400,000 B
  int*     flags  = (int*)    (ws + 33601600);      //          8 B
  inj_u16* wfrag  = (inj_u16*)(ws + 33601664);      //    131,072 B (wgf|wff)

  hipMemsetAsync(bhp, 0, (size_t)INJ_NB*64, stream);
  inj_flags  <<<1, 64, 0, stream>>>(eidx, (const inj_u32*)base, flags);
  inj_bhist  <<<INJ_PB, 256, 0, stream>>>(eidx, bhp, flags);
  inj_wfrag  <<<44, 256, 0, stream>>>(Wgate, Wfuse, Wp, Wg, wfrag, wpf, wgf2, flags);
  inj_bscan  <<<1, 256, 0, stream>>>(bhp, bbase, bcurA, rowp);
  inj_passA  <<<INJ_PB, 256, 0, stream>>>(eidx, bcurA, pairs, flags);
  inj_passB  <<<INJ_NB, 256, 0, stream>>>(pairs, bbase, rowp, dis, es);
  inj_projgcn<<<INJ_N/16, 256, 0, stream>>>(ev, bp, wpf, wgf2, dis, x, flags);
  InjectionLayer_91130616086689_kernel<<<INJ_N/16, 256, 0, stream>>>(
      base, bgate, bfuse, wfrag, wfrag + 32768,
      x, rowp, es, dis, bg, d_out, flags);
}